// Round 1
// baseline (508.039 us; speedup 1.0000x reference)
//
#include <hip/hip_runtime.h>

// Balloon-Windkessel BOLD model, explicit Euler, T=1000 steps, B=16384 sims.
// One thread per simulation; serial recurrence over T with a depth-8 register
// prefetch ring for the noise loads (only 256 waves exist -> no TLP to hide
// load latency, so ILP prefetch is mandatory).

#define T_STEPS 1000
#define BATCH   16384
#define DT        0.01f
#define NOISE_AMP 0.01f
#define V0        0.02f

#if __has_builtin(__builtin_amdgcn_exp2f)
#define EXP2F(x) __builtin_amdgcn_exp2f(x)
#else
#define EXP2F(x) exp2f(x)
#endif

__global__ __launch_bounds__(64) void balloon_kernel(
    const float* __restrict__ noise,
    const float* __restrict__ p_sigma,
    const float* __restrict__ p_mu,
    const float* __restrict__ p_lamb,
    const float* __restrict__ p_beta,
    const float* __restrict__ p_psi,
    const float* __restrict__ p_phi,
    const float* __restrict__ p_chi,
    float* __restrict__ out)
{
    const int b = blockIdx.x * 64 + threadIdx.x;

    const float sigma = p_sigma[0];
    const float mu    = p_mu[0];
    const float lamb  = p_lamb[0];
    const float beta  = p_beta[0];
    const float psi   = p_psi[0];
    const float phi   = p_phi[0];
    const float chi   = p_chi[0];

    // Loop-invariant precompute. lamb/beta are runtime scalars, so the
    // reciprocals are computed once with precise IEEE divide.
    const float lc       = log2f(1.0f - beta);   // log2(1-beta)
    const float inv_lamb = 1.0f / lamb;
    const float inv_beta = 1.0f / beta;
    const float dt_il    = DT * inv_lamb;

    float s = 0.0f, f = 1.0f, v = 1.0f, q = 1.0f;

    const float* np_ = noise + b;
    float*       op_ = out   + b;

    // Depth-8 prefetch ring (indices static after full unroll -> registers).
    constexpr int PF = 8;
    float zbuf[PF];
#pragma unroll
    for (int i = 0; i < PF; ++i) zbuf[i] = np_[i * BATCH];

    for (int tc = 0; tc < T_STEPS; tc += PF) {
#pragma unroll
        for (int i = 0; i < PF; ++i) {
            const int t = tc + i;
            const float z = zbuf[i];
            const int tp = t + PF;
            if (tp < T_STEPS) zbuf[i] = np_[tp * BATCH];   // prefetch t+8

            // E(f) = 1 - (1-beta)^(1/f) = 1 - exp2(log2(1-beta)/f)
            const float invf = __builtin_amdgcn_rcpf(f);
            const float E    = 1.0f - EXP2F(lc * invf);
            const float va   = v;                          // v^(1/alpha), alpha==1
            const float invv = __builtin_amdgcn_rcpf(v);

            const float s2 = s + DT * (NOISE_AMP * z - sigma * s - mu * (f - 1.0f));
            const float f2 = f + DT * s;
            const float v2 = v + dt_il * (f - va);
            const float q2 = q + dt_il * (f * E * inv_beta - va * q * invv);

            const float invv2 = __builtin_amdgcn_rcpf(v2);
            const float y = V0 * (phi * (1.0f - q2)
                                + psi * (1.0f - q2 * invv2)
                                + chi * (1.0f - v2));
            op_[t * BATCH] = y;

            s = s2; f = f2; v = v2; q = q2;
        }
    }
}

extern "C" void kernel_launch(void* const* d_in, const int* in_sizes, int n_in,
                              void* d_out, int out_size, void* d_ws, size_t ws_size,
                              hipStream_t stream) {
    const float* noise   = (const float*)d_in[0];
    const float* p_sigma = (const float*)d_in[1];
    const float* p_mu    = (const float*)d_in[2];
    const float* p_lamb  = (const float*)d_in[3];
    const float* p_beta  = (const float*)d_in[4];
    const float* p_psi   = (const float*)d_in[5];
    const float* p_phi   = (const float*)d_in[6];
    const float* p_chi   = (const float*)d_in[7];

    balloon_kernel<<<BATCH / 64, 64, 0, stream>>>(
        noise, p_sigma, p_mu, p_lamb, p_beta, p_psi, p_phi, p_chi,
        (float*)d_out);
}

// Round 2
// 187.400 us; speedup vs baseline: 2.7110x; 2.7110x over previous
//
#include <hip/hip_runtime.h>

// Balloon-Windkessel BOLD model, explicit Euler, T=1000 steps, B=16384 sims.
// One thread per sim (256 waves total -> 1 wave/CU, no TLP). The recurrence is
// serial in T, so the only latency-hiding tool is ILP: a double-buffered,
// branch-free prefetch pipeline 20 loads deep (20 steps of compute ~1200 cy
// covers the ~900 cy HBM round-trip). alpha==1 => v^(1/alpha)*q/v == q, which
// removes one rcp and two muls from the recurrence-carried chain.

#define T_STEPS 1000
#define BATCH   16384
#define DT        0.01f
#define NOISE_AMP 0.01f
#define V0        0.02f
#define PF        20          // 1000 = 50 * PF

#if __has_builtin(__builtin_amdgcn_exp2f)
#define EXP2F(x) __builtin_amdgcn_exp2f(x)
#else
#define EXP2F(x) exp2f(x)
#endif

struct Consts {
    float dtn;      // DT * NOISE_AMP
    float dts;      // DT * sigma
    float dtm;      // DT * mu
    float dt_il;    // DT / lamb
    float inv_beta; // 1 / beta
    float lc;       // log2(1 - beta)
    float c0;       // V0 * (phi + psi + chi)
    float c1;       // V0 * phi
    float c2;       // V0 * psi
    float c3;       // V0 * chi
};

// PF fully-unrolled Euler steps consuming noise from registers z[0..PF).
__device__ __forceinline__ void do_steps(const float z[PF], int tbase,
                                         float& s, float& f, float& v, float& q,
                                         float* __restrict__ op_, const Consts& c)
{
#pragma unroll
    for (int i = 0; i < PF; ++i) {
        const float zz   = z[i];
        // E(f) = 1 - (1-beta)^(1/f);  f*E/beta = g - g*exp2(lc/f), g = f/beta
        const float invf = __builtin_amdgcn_rcpf(f);
        const float e2   = EXP2F(c.lc * invf);
        const float g    = f * c.inv_beta;

        const float s2 = s + c.dtn * zz - c.dts * s - c.dtm * f + c.dtm;
        const float f2 = f + DT * s;
        const float v2 = v + c.dt_il * f - c.dt_il * v;       // v_a == v (alpha=1)
        const float h  = g - g * e2 - q;                      // f*E/beta - q
        const float q2 = q + c.dt_il * h;

        const float invv2 = __builtin_amdgcn_rcpf(v2);
        const float y = c.c0 - c.c1 * q2 - c.c2 * (q2 * invv2) - c.c3 * v2;
        op_[(tbase + i) * BATCH] = y;

        s = s2; f = f2; v = v2; q = q2;
    }
}

__global__ __launch_bounds__(64) void balloon_kernel(
    const float* __restrict__ noise,
    const float* __restrict__ p_sigma,
    const float* __restrict__ p_mu,
    const float* __restrict__ p_lamb,
    const float* __restrict__ p_beta,
    const float* __restrict__ p_psi,
    const float* __restrict__ p_phi,
    const float* __restrict__ p_chi,
    float* __restrict__ out)
{
    const int b = blockIdx.x * 64 + threadIdx.x;

    const float sigma = p_sigma[0];
    const float mu    = p_mu[0];
    const float lamb  = p_lamb[0];
    const float beta  = p_beta[0];
    const float psi   = p_psi[0];
    const float phi   = p_phi[0];
    const float chi   = p_chi[0];

    Consts c;
    c.dtn      = DT * NOISE_AMP;
    c.dts      = DT * sigma;
    c.dtm      = DT * mu;
    c.dt_il    = DT / lamb;      // precise divide, once
    c.inv_beta = 1.0f / beta;
    c.lc       = log2f(1.0f - beta);
    c.c0       = V0 * (phi + psi + chi);
    c.c1       = V0 * phi;
    c.c2       = V0 * psi;
    c.c3       = V0 * chi;

    float s = 0.0f, f = 1.0f, v = 1.0f, q = 1.0f;

    const float* np_ = noise + b;
    float*       op_ = out   + b;

    float za[PF], zb[PF];

    // Prologue: za <- t in [0, PF)
#pragma unroll
    for (int i = 0; i < PF; ++i) za[i] = np_[i * BATCH];

    // Main: 24 double-blocks of 2*PF = 960 steps, branch-free bodies.
    int t = 0;
#pragma unroll 1
    for (int blk = 0; blk < 24; ++blk) {
        // load zb <- [t+PF, t+2PF); compute [t, t+PF) from za
#pragma unroll
        for (int i = 0; i < PF; ++i) zb[i] = np_[(t + PF + i) * BATCH];
        do_steps(za, t, s, f, v, q, op_, c);
        t += PF;
        // load za <- [t+PF, t+2PF); compute [t, t+PF) from zb
#pragma unroll
        for (int i = 0; i < PF; ++i) za[i] = np_[(t + PF + i) * BATCH];
        do_steps(zb, t, s, f, v, q, op_, c);
        t += PF;
    }

    // t = 960. Epilogue: one more prefetching block, then the final block.
#pragma unroll
    for (int i = 0; i < PF; ++i) zb[i] = np_[(t + PF + i) * BATCH];  // [980,1000)
    do_steps(za, t, s, f, v, q, op_, c);   // [960, 980)
    t += PF;
    do_steps(zb, t, s, f, v, q, op_, c);   // [980, 1000), no loads
}

extern "C" void kernel_launch(void* const* d_in, const int* in_sizes, int n_in,
                              void* d_out, int out_size, void* d_ws, size_t ws_size,
                              hipStream_t stream) {
    const float* noise   = (const float*)d_in[0];
    const float* p_sigma = (const float*)d_in[1];
    const float* p_mu    = (const float*)d_in[2];
    const float* p_lamb  = (const float*)d_in[3];
    const float* p_beta  = (const float*)d_in[4];
    const float* p_psi   = (const float*)d_in[5];
    const float* p_phi   = (const float*)d_in[6];
    const float* p_chi   = (const float*)d_in[7];

    balloon_kernel<<<BATCH / 64, 64, 0, stream>>>(
        noise, p_sigma, p_mu, p_lamb, p_beta, p_psi, p_phi, p_chi,
        (float*)d_out);
}

// Round 3
// 166.691 us; speedup vs baseline: 3.0478x; 1.1242x over previous
//
#include <hip/hip_runtime.h>

// Balloon-Windkessel BOLD, explicit Euler, T=1000, B=16384. One thread/sim ->
// 256 waves, 1 wave/CU: no TLP, everything must come from ILP.
//  - exp2/rcp chain software-pipelined one step ahead (e2 for step t+1 is
//    computed during step t, starting from f_next which is the first op).
//  - invv tracked by a 2-FMA Newton update instead of per-step v_rcp.
//  - noise prefetch: register double-buffer, loads interleaved one-per-step
//    (distance 20 steps ~ >1500 cy) so no bulk waitcnt drain point.
//  - alpha==1 => v^(1/alpha)==v and v_a*q/v==q.

#define T_STEPS 1000
#define BATCH   16384
#define DT        0.01f
#define NOISE_AMP 0.01f
#define V0        0.02f
#define PF        20

#if __has_builtin(__builtin_amdgcn_exp2f)
#define EXP2F(x) __builtin_amdgcn_exp2f(x)
#else
#define EXP2F(x) exp2f(x)
#endif

__device__ __forceinline__ float uniform_f(float x) {
    return __uint_as_float(__builtin_amdgcn_readfirstlane(__float_as_uint(x)));
}

struct Consts {
    float as;     // 1 - DT*sigma
    float av;     // 1 - DT/lamb
    float dtn;    // DT * NOISE_AMP
    float dtm;    // DT * mu
    float dt_il;  // DT / lamb
    float kq;     // (DT/lamb) / beta
    float lc;     // log2(1 - beta)
    float c0;     // V0*(phi+psi+chi)
    float c1;     // V0*phi
    float c2;     // V0*psi
    float c3;     // V0*chi
};

// One Euler step. e2 = exp2(lc/f) precomputed for the CURRENT f (pipelined).
// Computes e2 for the next step from f_next, issued as early as possible.
__device__ __forceinline__ void step_one(float z,
                                         float& s, float& f, float& v, float& q,
                                         float& invv, float& e2,
                                         const Consts& c,
                                         float* __restrict__ op)
{
    // next-f first: feeds the long-latency rcp/exp2 pipe for step t+1
    const float f_next = __builtin_fmaf(DT, s, f);
    const float invf_n = __builtin_amdgcn_rcpf(f_next);

    // state updates (old s,f,v,q throughout)
    const float s_next = __builtin_fmaf(c.as, s,
                         __builtin_fmaf(c.dtn, z,
                         __builtin_fmaf(-c.dtm, f, c.dtm)));
    const float v_next = __builtin_fmaf(c.av, v, c.dt_il * f);
    const float t1     = __builtin_fmaf(-f, e2, f);        // f*(1-e2) = f*E
    const float q_next = __builtin_fmaf(c.av, q, c.kq * t1);

    const float e2_n   = EXP2F(c.lc * invf_n);             // for step t+1

    // Newton reciprocal tracking v (readout only; quadratically contracting)
    const float nres   = __builtin_fmaf(-v_next, invv, 2.0f);
    const float invv_n = invv * nres;

    // BOLD readout at new state
    const float p = q_next * invv_n;
    const float y = __builtin_fmaf(-c.c2, p,
                    __builtin_fmaf(-c.c3, v_next,
                    __builtin_fmaf(-c.c1, q_next, c.c0)));
    __builtin_nontemporal_store(y, op);

    s = s_next; f = f_next; v = v_next; q = q_next; invv = invv_n; e2 = e2_n;
}

__global__ __launch_bounds__(64, 1) void balloon_kernel(
    const float* __restrict__ noise,
    const float* __restrict__ p_sigma,
    const float* __restrict__ p_mu,
    const float* __restrict__ p_lamb,
    const float* __restrict__ p_beta,
    const float* __restrict__ p_psi,
    const float* __restrict__ p_phi,
    const float* __restrict__ p_chi,
    float* __restrict__ out)
{
    const int b = blockIdx.x * 64 + threadIdx.x;

    const float sigma = uniform_f(p_sigma[0]);
    const float mu    = uniform_f(p_mu[0]);
    const float lamb  = uniform_f(p_lamb[0]);
    const float beta  = uniform_f(p_beta[0]);
    const float psi   = uniform_f(p_psi[0]);
    const float phi   = uniform_f(p_phi[0]);
    const float chi   = uniform_f(p_chi[0]);

    Consts c;
    c.dt_il = DT / lamb;                 // precise divide, once
    c.as    = 1.0f - DT * sigma;
    c.av    = 1.0f - c.dt_il;
    c.dtn   = DT * NOISE_AMP;
    c.dtm   = DT * mu;
    c.kq    = c.dt_il / beta;
    c.lc    = log2f(1.0f - beta);
    c.c0    = V0 * (phi + psi + chi);
    c.c1    = V0 * phi;
    c.c2    = V0 * psi;
    c.c3    = V0 * chi;

    float s = 0.0f, f = 1.0f, v = 1.0f, q = 1.0f;
    float invv = 1.0f;
    float e2   = EXP2F(c.lc);            // exp2(lc/f0), f0 = 1

    const float* np_ = noise + b;
    float*       op_ = out   + b;

    float za[PF], zb[PF];

    // Prologue: za <- t in [0, PF). One-time latency hit.
#pragma unroll
    for (int i = 0; i < PF; ++i) za[i] = np_[i * BATCH];

    int t = 0;
#pragma unroll 1
    for (int blk = 0; blk < 24; ++blk) {
        // steps [t, t+PF) from za; per-step prefetch zb <- [t+PF, t+2PF)
#pragma unroll
        for (int i = 0; i < PF; ++i) {
            zb[i] = np_[(t + PF + i) * BATCH];
            step_one(za[i], s, f, v, q, invv, e2, c, op_ + (t + i) * BATCH);
        }
        t += PF;
#pragma unroll
        for (int i = 0; i < PF; ++i) {
            za[i] = np_[(t + PF + i) * BATCH];
            step_one(zb[i], s, f, v, q, invv, e2, c, op_ + (t + i) * BATCH);
        }
        t += PF;
    }

    // t = 960: last prefetching block, then final block with no loads.
#pragma unroll
    for (int i = 0; i < PF; ++i) {
        zb[i] = np_[(t + PF + i) * BATCH];               // [980, 1000)
        step_one(za[i], s, f, v, q, invv, e2, c, op_ + (t + i) * BATCH);
    }
    t += PF;
#pragma unroll
    for (int i = 0; i < PF; ++i) {
        step_one(zb[i], s, f, v, q, invv, e2, c, op_ + (t + i) * BATCH);
    }
}

extern "C" void kernel_launch(void* const* d_in, const int* in_sizes, int n_in,
                              void* d_out, int out_size, void* d_ws, size_t ws_size,
                              hipStream_t stream) {
    const float* noise   = (const float*)d_in[0];
    const float* p_sigma = (const float*)d_in[1];
    const float* p_mu    = (const float*)d_in[2];
    const float* p_lamb  = (const float*)d_in[3];
    const float* p_beta  = (const float*)d_in[4];
    const float* p_psi   = (const float*)d_in[5];
    const float* p_phi   = (const float*)d_in[6];
    const float* p_chi   = (const float*)d_in[7];

    balloon_kernel<<<BATCH / 64, 64, 0, stream>>>(
        noise, p_sigma, p_mu, p_lamb, p_beta, p_psi, p_phi, p_chi,
        (float*)d_out);
}

// Round 4
// 142.924 us; speedup vs baseline: 3.5546x; 1.1663x over previous
//
#include <hip/hip_runtime.h>

// Balloon-Windkessel BOLD, explicit Euler, T=1000, B=16384.
// alpha==1 makes v^(1/a)*q/v == q, which DECOUPLES the system into linear
// recurrences given f: (s,f) is an affine scan with constant 2x2 matrix A,
// and v,q are affine scans with constant scalar av = 1-DT/lamb. Only E(f)
// is nonlinear (pointwise). So we parallelize T:
//   20 chunks x 50 steps; block = 32 sims x 20 chunks = 640 threads.
//   P1: per-chunk (s,f) affine aggregate r_c          (load z)
//   scan1 (LDS, Hillis-Steele, weights A^(50*2^j))  -> chunk-start (s,f)
//   P2: replay chunk f_t, accumulate v,q aggregates   (reload z, L3-hot)
//   scan2 (scalar av^(50*2^j))                      -> chunk-start (v,q)
//   P3: replay, compute y, store                      (reload z)
// 512 blocks x 10 waves = 5120 waves = 20 waves/CU: TLP hides everything
// the 1-wave/CU versions (R1-R3, 410->80us) could not.
// Chunk-power matrices computed once in f64 to keep chunk-start rounding
// ~1e-6; P2/P3 replay f with IDENTICAL ops so v,q see one consistent f.

#define BATCH     16384
#define DT        0.01f
#define NOISE_AMP 0.01f
#define V0        0.02f
#define CHUNKS    20
#define CL        50          // 20 * 50 = 1000 steps
#define GSIMS     32
#define NTHREADS  (CHUNKS * GSIMS)   // 640

#if __has_builtin(__builtin_amdgcn_exp2f)
#define EXP2F(x) __builtin_amdgcn_exp2f(x)
#else
#define EXP2F(x) exp2f(x)
#endif

__device__ __forceinline__ float uf(float x) {
    return __uint_as_float(__builtin_amdgcn_readfirstlane(__float_as_uint(x)));
}

struct D22 { double a, b, c, d; };
__device__ __forceinline__ D22 dmul(D22 x, D22 y) {
    D22 r;
    r.a = x.a * y.a + x.b * y.c;  r.b = x.a * y.b + x.b * y.d;
    r.c = x.c * y.a + x.d * y.c;  r.d = x.c * y.b + x.d * y.d;
    return r;
}

__global__ __launch_bounds__(NTHREADS, 5) void balloon_scan(
    const float* __restrict__ noise,
    const float* __restrict__ p_sigma,
    const float* __restrict__ p_mu,
    const float* __restrict__ p_lamb,
    const float* __restrict__ p_beta,
    const float* __restrict__ p_psi,
    const float* __restrict__ p_phi,
    const float* __restrict__ p_chi,
    float* __restrict__ out)
{
    const int tid = threadIdx.x;
    const int g   = tid & (GSIMS - 1);   // sim within block
    const int cc  = tid >> 5;            // chunk 0..19
    const int sim = blockIdx.x * GSIMS + g;

    const float sigma = uf(p_sigma[0]);
    const float mu    = uf(p_mu[0]);
    const float lamb  = uf(p_lamb[0]);
    const float beta  = uf(p_beta[0]);
    const float psi   = uf(p_psi[0]);
    const float phi   = uf(p_phi[0]);
    const float chi   = uf(p_chi[0]);

    // ---- uniform fp32 step constants (identical forms to the validated R2) ----
    const float as_   = 1.0f - DT * sigma;
    const float dtn   = DT * NOISE_AMP;
    const float dtm   = DT * mu;
    const float dt_il = uf((float)(0.01 / (double)lamb));
    const float av    = 1.0f - dt_il;
    const float kq    = uf(dt_il / beta);
    const float lc    = uf(log2f(1.0f - beta));
    const float c0 = V0 * (phi + psi + chi), c1 = V0 * phi, c2 = V0 * psi, c3 = V0 * chi;

    // ---- chunk-power weights in f64, once: A^(50*2^j), av^(50*2^j) ----
    D22 A; A.a = 1.0 - 0.01 * (double)sigma; A.b = -0.01 * (double)mu;
           A.c = 0.01;                       A.d = 1.0;
    D22 A2 = dmul(A, A), A4 = dmul(A2, A2), A8 = dmul(A4, A4);
    D22 A16 = dmul(A8, A8), A32 = dmul(A16, A16);
    D22 P = dmul(dmul(A32, A16), A2);               // A^50
    double avd = 1.0 - 0.01 / (double)lamb;
    double av2 = avd * avd, av4 = av2 * av2, av8 = av4 * av4;
    double av16 = av8 * av8, av32 = av16 * av16;
    double ap = av32 * av16 * av2;                  // av^50

    float M11[5], M12[5], M21[5], M22[5], AVP[5];
#pragma unroll
    for (int j = 0; j < 5; ++j) {
        M11[j] = uf((float)P.a); M12[j] = uf((float)P.b);
        M21[j] = uf((float)P.c); M22[j] = uf((float)P.d);
        AVP[j] = uf((float)ap);
        P = dmul(P, P); ap = ap * ap;
    }

    // homogeneous parts at this thread's chunk start: A^(50c)*(0,1), av^(50c)*1
    float ws = 0.0f, wf = 1.0f, avc = 1.0f;
#pragma unroll
    for (int j = 0; j < 5; ++j) {
        if ((cc >> j) & 1) {
            float t = __builtin_fmaf(M11[j], ws, M12[j] * wf);
            wf = __builtin_fmaf(M21[j], ws, M22[j] * wf);
            ws = t;
            avc *= AVP[j];
        }
    }

    __shared__ float sA[NTHREADS];
    __shared__ float sB[NTHREADS];

    const float* zp = noise + cc * (CL * BATCH) + sim;

    // ---------------- P1: (s,f) chunk aggregate r_c ----------------
    float rs = 0.0f, rf = 0.0f;
#pragma unroll 10
    for (int j = 0; j < CL; ++j) {
        const float z = zp[j * BATCH];
        const float u = __builtin_fmaf(dtn, z, dtm);
        const float t = __builtin_fmaf(as_, rs, __builtin_fmaf(-dtm, rf, u));
        rf = __builtin_fmaf(DT, rs, rf);
        rs = t;
    }

    // ---------------- scan1: inclusive over chunks, matrix weights ----------------
    sA[tid] = rs; sB[tid] = rf;
    __syncthreads();
#pragma unroll
    for (int j = 0; j < 5; ++j) {
        const int off = 1 << j;
        float ns = 0.0f, nf = 0.0f;
        const bool has = (cc >= off);
        if (has) { ns = sA[tid - off * GSIMS]; nf = sB[tid - off * GSIMS]; }
        __syncthreads();
        if (has) {
            rs = __builtin_fmaf(M11[j], ns, __builtin_fmaf(M12[j], nf, rs));
            rf = __builtin_fmaf(M21[j], ns, __builtin_fmaf(M22[j], nf, rf));
            sA[tid] = rs; sB[tid] = rf;
        }
        __syncthreads();
    }
    float s0 = ws, f0 = wf;
    if (cc > 0) { s0 += sA[tid - GSIMS]; f0 += sB[tid - GSIMS]; }
    __syncthreads();   // sA/sB reads done; safe to reuse for scan2

    // ---------------- P2: replay f, accumulate v,q aggregates ----------------
    float s = s0, f = f0, Rv = 0.0f, Rq = 0.0f;
#pragma unroll 10
    for (int j = 0; j < CL; ++j) {
        const float z    = zp[j * BATCH];
        const float invf = __builtin_amdgcn_rcpf(f);
        const float e2   = EXP2F(lc * invf);
        const float t1   = __builtin_fmaf(-f, e2, f);       // f*E(f)
        Rv = __builtin_fmaf(av, Rv, dt_il * f);
        Rq = __builtin_fmaf(av, Rq, kq * t1);
        // canonical (s,f) step — MUST match P3 exactly
        const float s2 = __builtin_fmaf(as_, s,
                         __builtin_fmaf(dtn, z,
                         __builtin_fmaf(-dtm, f, dtm)));
        f = __builtin_fmaf(DT, s, f);
        s = s2;
    }

    // ---------------- scan2: scalar weights av^(50*2^j) ----------------
    sA[tid] = Rv; sB[tid] = Rq;
    __syncthreads();
#pragma unroll
    for (int j = 0; j < 5; ++j) {
        const int off = 1 << j;
        float nv = 0.0f, nq = 0.0f;
        const bool has = (cc >= off);
        if (has) { nv = sA[tid - off * GSIMS]; nq = sB[tid - off * GSIMS]; }
        __syncthreads();
        if (has) {
            Rv = __builtin_fmaf(AVP[j], nv, Rv);
            Rq = __builtin_fmaf(AVP[j], nq, Rq);
            sA[tid] = Rv; sB[tid] = Rq;
        }
        __syncthreads();
    }
    float v = avc, q = avc;                 // v0 = q0 = 1
    if (cc > 0) { v += sA[tid - GSIMS]; q += sB[tid - GSIMS]; }

    // ---------------- P3: replay, compute y, store ----------------
    s = s0; f = f0;
    float* op = out + cc * (CL * BATCH) + sim;
#pragma unroll 10
    for (int j = 0; j < CL; ++j) {
        const float z    = zp[j * BATCH];
        const float invf = __builtin_amdgcn_rcpf(f);
        const float e2   = EXP2F(lc * invf);
        const float t1   = __builtin_fmaf(-f, e2, f);
        const float vn   = __builtin_fmaf(av, v, dt_il * f);
        const float qn   = __builtin_fmaf(av, q, kq * t1);
        // canonical (s,f) step — identical to P2
        const float s2 = __builtin_fmaf(as_, s,
                         __builtin_fmaf(dtn, z,
                         __builtin_fmaf(-dtm, f, dtm)));
        f = __builtin_fmaf(DT, s, f);
        s = s2;

        const float invv = __builtin_amdgcn_rcpf(vn);
        const float y = __builtin_fmaf(-c2, qn * invv,
                        __builtin_fmaf(-c3, vn,
                        __builtin_fmaf(-c1, qn, c0)));
        op[j * BATCH] = y;
        v = vn; q = qn;
    }
}

extern "C" void kernel_launch(void* const* d_in, const int* in_sizes, int n_in,
                              void* d_out, int out_size, void* d_ws, size_t ws_size,
                              hipStream_t stream) {
    const float* noise   = (const float*)d_in[0];
    const float* p_sigma = (const float*)d_in[1];
    const float* p_mu    = (const float*)d_in[2];
    const float* p_lamb  = (const float*)d_in[3];
    const float* p_beta  = (const float*)d_in[4];
    const float* p_psi   = (const float*)d_in[5];
    const float* p_phi   = (const float*)d_in[6];
    const float* p_chi   = (const float*)d_in[7];

    balloon_scan<<<BATCH / GSIMS, NTHREADS, 0, stream>>>(
        noise, p_sigma, p_mu, p_lamb, p_beta, p_psi, p_phi, p_chi,
        (float*)d_out);
}